// Round 10
// baseline (472.403 us; speedup 1.0000x reference)
//
#include <hip/hip_runtime.h>

#define HSZ 32
#define TSEQ 2048
#define NBATCH 256

typedef float v2f __attribute__((ext_vector_type(2)));
typedef unsigned int v2u __attribute__((ext_vector_type(2)));

__device__ __forceinline__ v2f make2(float a, float b) {
    v2f r; r.x = a; r.y = b; return r;
}

__device__ __forceinline__ float hw_exp2(float x) {
#if __has_builtin(__builtin_amdgcn_exp2f)
    return __builtin_amdgcn_exp2f(x);
#else
    return exp2f(x);
#endif
}

__device__ __forceinline__ float hw_rcp(float x) {
#if __has_builtin(__builtin_amdgcn_rcpf)
    return __builtin_amdgcn_rcpf(x);
#else
    return 1.0f / x;
#endif
}

// Direction-agnostic cross-half combine: returns v[lane&31] + v[(lane&31)+32]
// in ALL lanes. (Proven R2-R8.)
__device__ __forceinline__ float half_sum(float v) {
#if __has_builtin(__builtin_amdgcn_permlane32_swap)
    v2u r = __builtin_amdgcn_permlane32_swap(__float_as_uint(v), __float_as_uint(v), false, false);
    return __uint_as_float(r.x) + __uint_as_float(r.y);
#else
    return v + __shfl_xor(v, 32, 64);
#endif
}

#if __has_builtin(__builtin_elementwise_fma)
#define PKFMA(a, b, cc) __builtin_elementwise_fma((a), (b), (cc))
#else
__device__ __forceinline__ v2f PKFMA(v2f a, v2f b, v2f c) {
    return make2(fmaf(a.x, b.x, c.x), fmaf(a.y, b.y, c.y));
}
#endif

// DPP lane-XOR moves within a 16-lane row (all lanes active):
//   XOR1 = quad_perm[1,0,3,2] = 0xB1
//   XOR2 = quad_perm[2,3,0,1] = 0x4E
//   XOR7 = row_half_mirror    = 0x141   (7-x == 7^x for 3-bit x)
//   XOR8 = row_ror:8          = 0x128   ((i+8)%16 == i^8)
#define DPPF(x, CTRL) \
    __uint_as_float(__builtin_amdgcn_mov_dpp(__float_as_uint(x), (CTRL), 0xF, 0xF, true))

__device__ __forceinline__ v2f dpp_pair(v2f s, int unused) { return s; }  // (not used)

// XOR distance covered at gather position p (single source of truth: the
// weight permutation below and the DPP tree use exactly this mapping).
__device__ __forceinline__ int gg(int p) {
    int v = 0;
    if (p & 1) v ^= 1;
    if (p & 2) v ^= 2;
    if (p & 4) v ^= 7;
    if (p & 8) v ^= 8;
    return v;
}

#define NL2E -1.44269504088896340736f   // -log2(e)
// Carried cell state is pre-scaled: cc = 2*log2e * c, so tanh(c) = 1 - 2*rcp(1+exp2(cc)).

__global__ __launch_bounds__(64, 1) void lstm_last_kernel(
    const float* __restrict__ x,      // [B, T, 1]
    const float* __restrict__ W_ih,   // [4H, 1]
    const float* __restrict__ W_hh,   // [4H, H]
    const float* __restrict__ b_ih,   // [4H]
    const float* __restrict__ b_hh,   // [4H]
    float* __restrict__ out)          // [B, H]
{
    const int b    = blockIdx.x;
    const int l    = threadIdx.x;   // 0..63
    const int k    = l & 31;        // hidden unit index
    const int half = l >> 5;        // 0: rows (i_k, g_k); 1: rows (f_k, o_k)
    const int row0 = l;             // i_k (half0) or f_k (half1)
    const int row1 = l + 64;        // g_k (half0) or o_k (half1)

    __shared__ float x_lds[TSEQ + 4];

    // ---- one-time staging: x row into LDS (float4, coalesced) ----
    const float4* xrow4 = (const float4*)(x + (size_t)b * TSEQ);
    float4* xl4 = (float4*)x_lds;
    #pragma unroll
    for (int j = 0; j < (TSEQ / 4) / 64; ++j)   // 8 iters
        xl4[j * 64 + l] = xrow4[j * 64 + l];
    if (l == 0) x_lds[TSEQ] = 0.0f;

    // ---- one-time: weights permuted by the gather order, pre-scaled ----
    // dot0 (i/f): * -log2e. dot1: g -> * -2log2e (tanh via sigma(2g)); o -> * -log2e.
    const float sc0 = NL2E;
    const float sc1 = half ? NL2E : 2.0f * NL2E;

    // Own-block (units k^g(p)) and other-block (units k^16^g(p)) weight pairs.
    v2f wA0p[8], wB0p[8], wA1p[8], wB1p[8];
    #pragma unroll
    for (int m = 0; m < 8; ++m) {
        int ia = k ^ gg(2*m), ib = k ^ gg(2*m + 1);
        int ja = ia ^ 16,     jb = ib ^ 16;
        wA0p[m] = make2(W_hh[row0*HSZ + ia] * sc0, W_hh[row0*HSZ + ib] * sc0);
        wB0p[m] = make2(W_hh[row0*HSZ + ja] * sc0, W_hh[row0*HSZ + jb] * sc0);
        wA1p[m] = make2(W_hh[row1*HSZ + ia] * sc1, W_hh[row1*HSZ + ib] * sc1);
        wB1p[m] = make2(W_hh[row1*HSZ + ja] * sc1, W_hh[row1*HSZ + jb] * sc1);
    }
    const float wx0   = W_ih[row0] * sc0;
    const float wx1   = W_ih[row1] * sc1;
    const float bias0 = (b_ih[row0] + b_hh[row0]) * sc0;
    const float bias1 = (b_ih[row1] + b_hh[row1]) * sc1;

    // a1 (half0) = S*tanh(g), S = 2*log2e = -2*NL2E: a1 = 2S*sigma(2g) - S
    const float s1mul = half ? 1.0f : -4.0f * NL2E;
    const float s1add = half ? 0.0f :  2.0f * NL2E;

    float cc    = 0.0f;   // scaled cell state: 2*log2e * c
    float h_own = 0.0f;   // h_{k}, valid in ALL lanes

    __syncthreads();
    float xt = x_lds[0];

    #pragma unroll 1
    for (int t = 0; t < TSEQ; ++t) {
        // ---- all-gather of h: 1 ds_swizzle (lane^16, involution) + 30 DPP ----
        float s0 = h_own;
        float t0 = __uint_as_float(
            __builtin_amdgcn_ds_swizzle(__float_as_uint(h_own), 0x401F)); // lane^16
        float xt_next = x_lds[t + 1];   // prefetch behind the swizzle

        v2f sp0 = make2(s0, DPPF(s0, 0xB1));
        v2f sp1 = make2(DPPF(sp0.x, 0x4E),  DPPF(sp0.y, 0x4E));
        v2f sp2 = make2(DPPF(sp0.x, 0x141), DPPF(sp0.y, 0x141));
        v2f sp3 = make2(DPPF(sp1.x, 0x141), DPPF(sp1.y, 0x141));
        v2f sp4 = make2(DPPF(sp0.x, 0x128), DPPF(sp0.y, 0x128));
        v2f sp5 = make2(DPPF(sp1.x, 0x128), DPPF(sp1.y, 0x128));
        v2f sp6 = make2(DPPF(sp2.x, 0x128), DPPF(sp2.y, 0x128));
        v2f sp7 = make2(DPPF(sp3.x, 0x128), DPPF(sp3.y, 0x128));

        // ---- own-block FMAs (no DS dependency) ----
        v2f z = make2(0.f, 0.f);
        v2f c00 = PKFMA(wA0p[0], sp0, make2(fmaf(wx0, xt, bias0), 0.f));
        v2f c01 = PKFMA(wA0p[1], sp1, z);
        v2f c02 = PKFMA(wA0p[2], sp2, z);
        v2f c03 = PKFMA(wA0p[3], sp3, z);
        c00 = PKFMA(wA0p[4], sp4, c00);
        c01 = PKFMA(wA0p[5], sp5, c01);
        c02 = PKFMA(wA0p[6], sp6, c02);
        c03 = PKFMA(wA0p[7], sp7, c03);
        v2f c10 = PKFMA(wA1p[0], sp0, make2(fmaf(wx1, xt, bias1), 0.f));
        v2f c11 = PKFMA(wA1p[1], sp1, z);
        v2f c12 = PKFMA(wA1p[2], sp2, z);
        v2f c13 = PKFMA(wA1p[3], sp3, z);
        c10 = PKFMA(wA1p[4], sp4, c10);
        c11 = PKFMA(wA1p[5], sp5, c11);
        c12 = PKFMA(wA1p[6], sp6, c12);
        c13 = PKFMA(wA1p[7], sp7, c13);

        // ---- other-block tree (after swizzle returns) + FMAs ----
        v2f tp0 = make2(t0, DPPF(t0, 0xB1));
        v2f tp1 = make2(DPPF(tp0.x, 0x4E),  DPPF(tp0.y, 0x4E));
        v2f tp2 = make2(DPPF(tp0.x, 0x141), DPPF(tp0.y, 0x141));
        v2f tp3 = make2(DPPF(tp1.x, 0x141), DPPF(tp1.y, 0x141));
        v2f tp4 = make2(DPPF(tp0.x, 0x128), DPPF(tp0.y, 0x128));
        v2f tp5 = make2(DPPF(tp1.x, 0x128), DPPF(tp1.y, 0x128));
        v2f tp6 = make2(DPPF(tp2.x, 0x128), DPPF(tp2.y, 0x128));
        v2f tp7 = make2(DPPF(tp3.x, 0x128), DPPF(tp3.y, 0x128));

        c00 = PKFMA(wB0p[0], tp0, c00);
        c01 = PKFMA(wB0p[1], tp1, c01);
        c02 = PKFMA(wB0p[2], tp2, c02);
        c03 = PKFMA(wB0p[3], tp3, c03);
        c00 = PKFMA(wB0p[4], tp4, c00);
        c01 = PKFMA(wB0p[5], tp5, c01);
        c02 = PKFMA(wB0p[6], tp6, c02);
        c03 = PKFMA(wB0p[7], tp7, c03);
        c10 = PKFMA(wB1p[0], tp0, c10);
        c11 = PKFMA(wB1p[1], tp1, c11);
        c12 = PKFMA(wB1p[2], tp2, c12);
        c13 = PKFMA(wB1p[3], tp3, c13);
        c10 = PKFMA(wB1p[4], tp4, c10);
        c11 = PKFMA(wB1p[5], tp5, c11);
        c12 = PKFMA(wB1p[6], tp6, c12);
        c13 = PKFMA(wB1p[7], tp7, c13);

        v2f r0v = (c00 + c01) + (c02 + c03);
        v2f r1v = (c10 + c11) + (c12 + c13);
        float d0 = r0v.x + r0v.y;   // i (half0) / f (half1), pre-scaled
        float d1 = r1v.x + r1v.y;   // g (half0) / o (half1), pre-scaled

        float a0 = hw_rcp(1.0f + hw_exp2(d0));                     // sigmoid(i/f)
        float a1 = fmaf(s1mul, hw_rcp(1.0f + hw_exp2(d1)), s1add); // S*tanh(g) / sigm(o)

        // o in ALL lanes (direction-agnostic): asum = a1_half0 + a1_half1
        float asum  = half_sum(a1);
        float o_all = half ? a1 : (asum - a1);

        // c update: half0 piece i*(S*tanh g) = S*(i*g); half1 piece f*cc_old.
        float v  = a0 * (half ? cc : a1);
        float cn = half_sum(v);
        cc = cn;

        // tanh(c) = 1 - 2*rcp(1+exp2(cc)); h = o * tanh(c), valid in all lanes
        float r2 = hw_rcp(1.0f + hw_exp2(cn));
        float th = fmaf(-2.0f, r2, 1.0f);
        h_own = o_all * th;

        xt = xt_next;
    }

    if (half == 0) out[b * HSZ + k] = h_own;
}

extern "C" void kernel_launch(void* const* d_in, const int* in_sizes, int n_in,
                              void* d_out, int out_size, void* d_ws, size_t ws_size,
                              hipStream_t stream) {
    const float* x    = (const float*)d_in[0];
    const float* W_ih = (const float*)d_in[1];
    const float* W_hh = (const float*)d_in[2];
    const float* b_ih = (const float*)d_in[3];
    const float* b_hh = (const float*)d_in[4];
    float* out = (float*)d_out;

    lstm_last_kernel<<<NBATCH, 64, 0, stream>>>(x, W_ih, W_hh, b_ih, b_hh, out);
}